// Round 11
// baseline (51.057 us; speedup 1.0000x reference)
//
#include <hip/hip_runtime.h>
#include <hip/hip_bf16.h>

typedef __attribute__((ext_vector_type(8))) short bf16x8;
typedef __attribute__((ext_vector_type(4))) float f32x4;

__device__ __forceinline__ short f2bf(float x) {
    __hip_bfloat16 t = __float2bfloat16(x);
    return __builtin_bit_cast(short, t);
}

// B=16, N=4096, K=16, hidden=64, dim=64
// R11 = R10 (50.5us champion: NT/plain 2MB stripe) with ONE change:
// ALL idx/dist loads hoisted to a per-wave prologue and parked in LDS.
// Steady-state VMEM stream = stores + L2-resident xyz gathers only, so
// DRAM sees a pure write stream (no R/W turnaround) like the fill kernel.

__global__ __launch_bounds__(256, 3) void ppe_kernel(
    const float* __restrict__ xyz,   // [16,4096,3]
    const float* __restrict__ dist,  // [16,4096,16]
    const float* __restrict__ W1,    // [10,64]
    const float* __restrict__ b1,    // [64]
    const float* __restrict__ W2,    // [64,64]
    const float* __restrict__ b2,    // [64]
    const int*   __restrict__ idx,   // [16,4096,16] (int32)
    float* __restrict__ out)         // [16,4096,16,64]
{
    __shared__ float sbuf[4][1024];      // 16 KB: per-wave store staging
    __shared__ int   s_idx[4][24 * 16];  // 6 KB: per-wave idx table
    __shared__ float s_dst[4][24 * 16];  // 6 KB: per-wave dist table

    const int lane = threadIdx.x & 63;
    const int warp = threadIdx.x >> 6;
    const int wid  = (blockIdx.x * blockDim.x + threadIdx.x) >> 6; // 0..3071
    const int u    = lane >> 4;   // 0..3
    const int p    = lane & 15;   // 0..15

    float* const ws = &sbuf[warp][0];
    int*   const sI = &s_idx[warp][0];
    float* const sD = &s_dst[warp][0];

    // ---- persistent weight fragments (identical to R5) ----
    bf16x8 w1f[4];
#pragma unroll
    for (int t = 0; t < 4; ++t) {
        const int hu = 16 * t + p;
#pragma unroll
        for (int j = 0; j < 8; ++j) {
            float coef;
            if (j < 3)      coef = W1[j * 64 + hu] + W1[(6 + j) * 64 + hu];
            else if (j < 6) coef = W1[j * 64 + hu] - W1[(j + 3) * 64 + hu];
            else if (j == 6) coef = W1[9 * 64 + hu];
            else             coef = b1[hu];
            w1f[t][j] = (u == 0) ? f2bf(coef) : (short)0;
        }
    }

    bf16x8 w2f[4][2];
#pragma unroll
    for (int dt = 0; dt < 4; ++dt)
#pragma unroll
        for (int kt = 0; kt < 2; ++kt)
#pragma unroll
            for (int j = 0; j < 8; ++j) {
                const int unit = 32 * kt + 16 * (j >> 2) + 4 * u + (j & 3);
                w2f[dt][kt][j] = f2bf(W2[unit * 64 + 16 * dt + p]);
            }

    float b2r[4][4];
#pragma unroll
    for (int dt = 0; dt < 4; ++dt)
#pragma unroll
        for (int r = 0; r < 4; ++r)
            b2r[dt][r] = b2[16 * dt + 4 * u + r];

    const short one_bf = f2bf(1.0f);
    const int NG = 65536, S = 3072;
    const int g0 = wid;
    const int tcount = (NG - 1 - g0) / S + 1;   // 21 or 22

    // ---- prologue A: park ALL idx/dist for this wave's iterations in LDS ----
    // lane (u,p) handles table row tt=tb+u, element p: contiguous 64-dword
    // writes per step (conflict-free). Dummy rows re-load g0 (harmless).
#pragma unroll
    for (int tb = 0; tb < 24; tb += 4) {
        const int tt = tb + u;
        int gt = g0 + tt * S;
        if (tt >= tcount) gt = g0;
        const int row = gt * 16 + p;
        sI[tt * 16 + p] = idx[row];
        sD[tt * 16 + p] = dist[row];
    }
    // wave-private: lgkmcnt/vmcnt ordering is handled by the compiler.

    // ---- prologue B: operands for t=0 ----
    int   nb0 = sI[p];
    float dC  = sD[p];
    const float* cp0 = xyz + (size_t)g0 * 3;
    float cC0 = cp0[0], cC1 = cp0[1], cC2 = cp0[2];
    const float* np0 = xyz + ((size_t)((g0 >> 12) * 4096) + nb0) * 3;
    float nC0 = np0[0], nC1 = np0[1], nC2 = np0[2];

    int t = 0;
    for (int g = g0; g < NG; g += S, ++t) {
        int gB = g + S; if (gB >= NG) gB = g;       // t+1 (clamped dummy)
        int tn = t + 1; if (tn >= tcount) tn = t;

        // ---- 1. next iteration's idx/dist from LDS (broadcast reads) ----
        const int   nbN = sI[tn * 16 + p];
        const float dN  = sD[tn * 16 + p];

        // ---- 2. issue xyz loads for t+1 (L2-resident, never DRAM) ----
        const float* cpn = xyz + (size_t)gB * 3;
        float cL0 = cpn[0], cL1 = cpn[1], cL2 = cpn[2];
        const float* npn = xyz + ((size_t)((gB >> 12) * 4096) + nbN) * 3;
        float nL0 = npn[0], nL1 = npn[1], nL2 = npn[2];

        // ---- 3. layer-1 MFMA ----
        bf16x8 fa;
        fa[0] = f2bf(cC0); fa[1] = f2bf(cC1); fa[2] = f2bf(cC2);
        fa[3] = f2bf(nC0); fa[4] = f2bf(nC1); fa[5] = f2bf(nC2);
        fa[6] = f2bf(dC);  fa[7] = one_bf;

        f32x4 acc1[4];
#pragma unroll
        for (int tt = 0; tt < 4; ++tt) {
            acc1[tt] = (f32x4){0.f, 0.f, 0.f, 0.f};
            acc1[tt] = __builtin_amdgcn_mfma_f32_16x16x32_bf16(w1f[tt], fa, acc1[tt], 0, 0, 0);
            acc1[tt][0] = fmaxf(acc1[tt][0], 0.f);
            acc1[tt][1] = fmaxf(acc1[tt][1], 0.f);
            acc1[tt][2] = fmaxf(acc1[tt][2], 0.f);
            acc1[tt][3] = fmaxf(acc1[tt][3], 0.f);
        }

        // ---- 4. layer-2 B-frag directly from acc1 (permutation-matched) ----
        bf16x8 hb[2];
#pragma unroll
        for (int kt = 0; kt < 2; ++kt)
#pragma unroll
            for (int j = 0; j < 8; ++j)
                hb[kt][j] = f2bf(acc1[2 * kt + (j >> 2)][j & 3]);

        // ---- 5. layer-2 MFMA, bias in C-init: D2[dim][pt] ----
        f32x4 acc2[4];
#pragma unroll
        for (int dt = 0; dt < 4; ++dt) {
            acc2[dt] = (f32x4){b2r[dt][0], b2r[dt][1], b2r[dt][2], b2r[dt][3]};
            acc2[dt] = __builtin_amdgcn_mfma_f32_16x16x32_bf16(w2f[dt][0], hb[0], acc2[dt], 0, 0, 0);
            acc2[dt] = __builtin_amdgcn_mfma_f32_16x16x32_bf16(w2f[dt][1], hb[1], acc2[dt], 0, 0, 0);
        }

        // ---- 6. transpose via LDS (swizzled, conflict-free) ----
#pragma unroll
        for (int dt = 0; dt < 4; ++dt) {
            const int col = (16 * dt + 4 * u) ^ ((p & 1) << 4);
            *(f32x4*)&ws[p * 64 + col] = acc2[dt];
        }

        // ---- 7. LDS -> 4x 1KB contiguous stores; NT/plain striped at 2MB ----
        float* const obase = out + (size_t)g * 1024;
        if ((g >> 9) & 1) {
#pragma unroll
            for (int i = 0; i < 4; ++i) {
                const int pt = 4 * i + u;
                f32x4 v = *(const f32x4*)&ws[pt * 64 + ((4 * p) ^ ((u & 1) << 4))];
                __builtin_nontemporal_store(v, (f32x4*)&obase[i * 256 + lane * 4]);
            }
        } else {
#pragma unroll
            for (int i = 0; i < 4; ++i) {
                const int pt = 4 * i + u;
                f32x4 v = *(const f32x4*)&ws[pt * 64 + ((4 * p) ^ ((u & 1) << 4))];
                *(f32x4*)&obase[i * 256 + lane * 4] = v;
            }
        }

        // ---- 8. rotate pipeline registers ----
        cC0 = cL0; cC1 = cL1; cC2 = cL2;
        nC0 = nL0; nC1 = nL1; nC2 = nL2;
        dC  = dN;
    }
}

extern "C" void kernel_launch(void* const* d_in, const int* in_sizes, int n_in,
                              void* d_out, int out_size, void* d_ws, size_t ws_size,
                              hipStream_t stream) {
    const float* xyz  = (const float*)d_in[0];
    const float* dist = (const float*)d_in[1];
    const float* W1   = (const float*)d_in[2];
    const float* b1   = (const float*)d_in[3];
    const float* W2   = (const float*)d_in[4];
    const float* b2   = (const float*)d_in[5];
    const int*   idx  = (const int*)d_in[6];
    float* out = (float*)d_out;

    ppe_kernel<<<dim3(768), dim3(256), 0, stream>>>(xyz, dist, W1, b1, W2, b2, idx, out);
}